// Round 1
// baseline (9500.537 us; speedup 1.0000x reference)
//
#include <hip/hip_runtime.h>
#include <math.h>

#define L_SEQ 2048
#define DM 1024
#define DFF 4096
#define NH 16
#define HD 64

// ---------------- conv_in + relu + transpose: x[4,L] -> h[L, DM] ----------------
__global__ __launch_bounds__(256) void conv_in_kernel(const float* __restrict__ x,
                                                      const float* __restrict__ w,
                                                      const float* __restrict__ b,
                                                      float* __restrict__ h) {
    int gid = blockIdx.x * 256 + threadIdx.x;   // L*DM threads
    int d = gid & (DM - 1);
    int l = gid >> 10;
    float acc = b[d];
    const float* wd = w + d * 28;               // [c][k], 4*7
#pragma unroll
    for (int c = 0; c < 4; ++c) {
#pragma unroll
        for (int k = 0; k < 7; ++k) {
            int t = l + k - 6;
            float xv = (t >= 0) ? x[c * L_SEQ + t] : 0.f;
            acc = fmaf(xv, wd[c * 7 + k], acc);
        }
    }
    h[(size_t)l * DM + d] = fmaxf(acc, 0.f);
}

// ---------------- RMSNorm: out[l,:] = h[l,:]*rsqrt(mean(h^2)+eps)*w + b ----------------
__global__ __launch_bounds__(256) void rmsnorm_kernel(const float* __restrict__ h,
                                                      const float* __restrict__ w,
                                                      const float* __restrict__ b,
                                                      float* __restrict__ out) {
    int l = blockIdx.x;
    int t = threadIdx.x;
    const float* row = h + (size_t)l * DM;
    float4 xv = *(const float4*)(row + t * 4);
    float ss = xv.x * xv.x + xv.y * xv.y + xv.z * xv.z + xv.w * xv.w;
#pragma unroll
    for (int off = 1; off < 64; off <<= 1) ss += __shfl_xor(ss, off, 64);
    __shared__ float red[4];
    if ((t & 63) == 0) red[t >> 6] = ss;
    __syncthreads();
    float tot = red[0] + red[1] + red[2] + red[3];
    float inv = rsqrtf(tot * (1.f / DM) + 1e-5f);
    float4 wv = *(const float4*)(w + t * 4);
    float4 bv = *(const float4*)(b + t * 4);
    float4 ov;
    ov.x = fmaf(xv.x * inv, wv.x, bv.x);
    ov.y = fmaf(xv.y * inv, wv.y, bv.y);
    ov.z = fmaf(xv.z * inv, wv.z, bv.z);
    ov.w = fmaf(xv.w * inv, wv.w, bv.w);
    *(float4*)(out + (size_t)l * DM + t * 4) = ov;
}

// ---------------- GEMM NT: C[M,N] = (res?) + (bias?) + A[M,K] * B[N,K]^T, (relu?) ----------------
// 128x64 tile, BK=16, 256 threads, 8x4 micro-tile.
template <bool BIAS, bool RELU, bool RES>
__global__ __launch_bounds__(256) void gemm_nt(const float* __restrict__ A,
                                               const float* __restrict__ B,
                                               const float* __restrict__ bias,
                                               const float* __restrict__ res,
                                               float* __restrict__ C,
                                               int M, int N, int K) {
    __shared__ float As[16][132];
    __shared__ float Bs[16][68];
    const int t = threadIdx.x;
    const int tx = t & 15;   // n dir
    const int ty = t >> 4;   // m dir
    const int m0 = blockIdx.y * 128;
    const int n0 = blockIdx.x * 64;

    float acc[8][4];
#pragma unroll
    for (int i = 0; i < 8; ++i)
#pragma unroll
        for (int j = 0; j < 4; ++j) acc[i][j] = 0.f;

    const int arow = t >> 2;         // 0..63
    const int akq = (t & 3) * 4;     // 0,4,8,12

    for (int k0 = 0; k0 < K; k0 += 16) {
        float4 av0 = *(const float4*)(A + (size_t)(m0 + arow) * K + k0 + akq);
        float4 av1 = *(const float4*)(A + (size_t)(m0 + arow + 64) * K + k0 + akq);
        float4 bv = *(const float4*)(B + (size_t)(n0 + arow) * K + k0 + akq);
        As[akq + 0][arow] = av0.x;
        As[akq + 1][arow] = av0.y;
        As[akq + 2][arow] = av0.z;
        As[akq + 3][arow] = av0.w;
        As[akq + 0][arow + 64] = av1.x;
        As[akq + 1][arow + 64] = av1.y;
        As[akq + 2][arow + 64] = av1.z;
        As[akq + 3][arow + 64] = av1.w;
        Bs[akq + 0][arow] = bv.x;
        Bs[akq + 1][arow] = bv.y;
        Bs[akq + 2][arow] = bv.z;
        Bs[akq + 3][arow] = bv.w;
        __syncthreads();
#pragma unroll
        for (int kk = 0; kk < 16; ++kk) {
            float4 a0 = *(const float4*)(&As[kk][ty * 8]);
            float4 a1 = *(const float4*)(&As[kk][ty * 8 + 4]);
            float4 b0 = *(const float4*)(&Bs[kk][tx * 4]);
            float am[8] = {a0.x, a0.y, a0.z, a0.w, a1.x, a1.y, a1.z, a1.w};
            float bn[4] = {b0.x, b0.y, b0.z, b0.w};
#pragma unroll
            for (int i = 0; i < 8; ++i)
#pragma unroll
                for (int j = 0; j < 4; ++j) acc[i][j] = fmaf(am[i], bn[j], acc[i][j]);
        }
        __syncthreads();
    }

    float4 bb;
    if (BIAS) bb = *(const float4*)(bias + n0 + tx * 4);
#pragma unroll
    for (int i = 0; i < 8; ++i) {
        int m = m0 + ty * 8 + i;
        float4 ov = {acc[i][0], acc[i][1], acc[i][2], acc[i][3]};
        if (BIAS) { ov.x += bb.x; ov.y += bb.y; ov.z += bb.z; ov.w += bb.w; }
        if (RELU) {
            ov.x = fmaxf(ov.x, 0.f); ov.y = fmaxf(ov.y, 0.f);
            ov.z = fmaxf(ov.z, 0.f); ov.w = fmaxf(ov.w, 0.f);
        }
        if (RES) {
            float4 rv = *(const float4*)(res + (size_t)m * N + n0 + tx * 4);
            ov.x += rv.x; ov.y += rv.y; ov.z += rv.z; ov.w += rv.w;
        }
        *(float4*)(C + (size_t)m * N + n0 + tx * 4) = ov;
    }
}

// ---------------- RoPE (NeoX rotate-half), applied in-place to q and k ----------------
__global__ __launch_bounds__(256) void rope_kernel(float* __restrict__ q, float* __restrict__ k) {
    int gid = blockIdx.x * 256 + threadIdx.x;  // L*NH*32
    int j = gid & 31;
    int hh = (gid >> 5) & 15;
    int l = gid >> 9;
    float freq = powf(10000.f, -(float)(2 * j) * (1.f / 64.f));
    float ang = (float)l * freq;
    float s = sinf(ang), c = cosf(ang);
    size_t base = (size_t)l * DM + hh * HD + j;
    float q1 = q[base], q2 = q[base + 32];
    q[base] = q1 * c - q2 * s;
    q[base + 32] = q2 * c + q1 * s;
    float k1 = k[base], k2 = k[base + 32];
    k[base] = k1 * c - k2 * s;
    k[base + 32] = k2 * c + k1 * s;
}

// ---------------- Flash-style causal attention, fp32 ----------------
// grid: (NH, L/64). One block per (head, 64-row q-tile). 256 threads: row r=t>>2, seg c4=t&3.
__global__ __launch_bounds__(256) void attn_kernel(const float* __restrict__ q,
                                                   const float* __restrict__ k,
                                                   const float* __restrict__ v,
                                                   float* __restrict__ o) {
    __shared__ float Qs[64][68];   // [r][d]
    __shared__ float KP[64][68];   // phase 1: K^T [d][j]; phase 2: P [r][j]
    __shared__ float Vs[64][68];   // [j][d]
    const int t = threadIdx.x;
    const int h = blockIdx.x;
    const int qt = blockIdx.y;
    const int l0 = qt * 64;
    const int r = t >> 2;
    const int c4 = t & 3;
    const int dseg = c4 * 16;

    // load Q tile (scaled by 1/sqrt(HD))
#pragma unroll
    for (int i = 0; i < 4; ++i) {
        int f = t + i * 256;         // 0..1023 float4s
        int row = f >> 4;
        int dd = (f & 15) * 4;
        float4 qv = *(const float4*)(q + (size_t)(l0 + row) * DM + h * HD + dd);
        qv.x *= 0.125f; qv.y *= 0.125f; qv.z *= 0.125f; qv.w *= 0.125f;
        *(float4*)(&Qs[row][dd]) = qv;
    }

    float m_r = -1e30f, l_r = 0.f;
    float O[16];
#pragma unroll
    for (int i = 0; i < 16; ++i) O[i] = 0.f;

    const int ntiles = qt + 1;
    for (int jt = 0; jt < ntiles; ++jt) {
        const int j0 = jt * 64;
        __syncthreads();  // prior-iteration reads of KP/Vs done
        // load K (transposed) and V tiles
#pragma unroll
        for (int i = 0; i < 4; ++i) {
            int f = t + i * 256;
            int row = f >> 4;
            int dd = (f & 15) * 4;
            float4 kv = *(const float4*)(k + (size_t)(j0 + row) * DM + h * HD + dd);
            KP[dd + 0][row] = kv.x;
            KP[dd + 1][row] = kv.y;
            KP[dd + 2][row] = kv.z;
            KP[dd + 3][row] = kv.w;
            float4 vv = *(const float4*)(v + (size_t)(j0 + row) * DM + h * HD + dd);
            *(float4*)(&Vs[row][dd]) = vv;
        }
        __syncthreads();

        // S = Q K^T for this thread's 16 keys (j = dseg..dseg+15) of row r
        float s[16];
#pragma unroll
        for (int jj = 0; jj < 16; ++jj) s[jj] = 0.f;
#pragma unroll 4
        for (int d = 0; d < 64; ++d) {
            float qv = Qs[r][d];
            float4 k0 = *(const float4*)(&KP[d][dseg]);
            float4 k1 = *(const float4*)(&KP[d][dseg + 4]);
            float4 k2 = *(const float4*)(&KP[d][dseg + 8]);
            float4 k3 = *(const float4*)(&KP[d][dseg + 12]);
            s[0] = fmaf(qv, k0.x, s[0]);   s[1] = fmaf(qv, k0.y, s[1]);
            s[2] = fmaf(qv, k0.z, s[2]);   s[3] = fmaf(qv, k0.w, s[3]);
            s[4] = fmaf(qv, k1.x, s[4]);   s[5] = fmaf(qv, k1.y, s[5]);
            s[6] = fmaf(qv, k1.z, s[6]);   s[7] = fmaf(qv, k1.w, s[7]);
            s[8] = fmaf(qv, k2.x, s[8]);   s[9] = fmaf(qv, k2.y, s[9]);
            s[10] = fmaf(qv, k2.z, s[10]); s[11] = fmaf(qv, k2.w, s[11]);
            s[12] = fmaf(qv, k3.x, s[12]); s[13] = fmaf(qv, k3.y, s[13]);
            s[14] = fmaf(qv, k3.z, s[14]); s[15] = fmaf(qv, k3.w, s[15]);
        }
        if (jt == qt) {  // causal mask on diagonal tile: key j valid iff j <= r
#pragma unroll
            for (int jj = 0; jj < 16; ++jj)
                if (dseg + jj > r) s[jj] = -1e30f;
        }
        // online softmax update (4 threads per row cooperate via shfl)
        float mt = s[0];
#pragma unroll
        for (int jj = 1; jj < 16; ++jj) mt = fmaxf(mt, s[jj]);
        mt = fmaxf(mt, __shfl_xor(mt, 1, 64));
        mt = fmaxf(mt, __shfl_xor(mt, 2, 64));
        float m_new = fmaxf(m_r, mt);
        float alpha = __expf(m_r - m_new);
        float rs = 0.f;
#pragma unroll
        for (int jj = 0; jj < 16; ++jj) {
            float p = __expf(s[jj] - m_new);
            s[jj] = p;
            rs += p;
        }
        rs += __shfl_xor(rs, 1, 64);
        rs += __shfl_xor(rs, 2, 64);
        l_r = l_r * alpha + rs;
        m_r = m_new;
#pragma unroll
        for (int i = 0; i < 16; ++i) O[i] *= alpha;

        __syncthreads();  // all KP (K^T) reads done before overwrite as P
        *(float4*)(&KP[r][dseg]) = make_float4(s[0], s[1], s[2], s[3]);
        *(float4*)(&KP[r][dseg + 4]) = make_float4(s[4], s[5], s[6], s[7]);
        *(float4*)(&KP[r][dseg + 8]) = make_float4(s[8], s[9], s[10], s[11]);
        *(float4*)(&KP[r][dseg + 12]) = make_float4(s[12], s[13], s[14], s[15]);
        __syncthreads();

        // O[r][dseg..dseg+15] += P[r][:] @ V[:, dseg..dseg+15]
#pragma unroll 4
        for (int j = 0; j < 64; ++j) {
            float pv = KP[r][j];
            float4 v0 = *(const float4*)(&Vs[j][dseg]);
            float4 v1 = *(const float4*)(&Vs[j][dseg + 4]);
            float4 v2 = *(const float4*)(&Vs[j][dseg + 8]);
            float4 v3 = *(const float4*)(&Vs[j][dseg + 12]);
            O[0] = fmaf(pv, v0.x, O[0]);   O[1] = fmaf(pv, v0.y, O[1]);
            O[2] = fmaf(pv, v0.z, O[2]);   O[3] = fmaf(pv, v0.w, O[3]);
            O[4] = fmaf(pv, v1.x, O[4]);   O[5] = fmaf(pv, v1.y, O[5]);
            O[6] = fmaf(pv, v1.z, O[6]);   O[7] = fmaf(pv, v1.w, O[7]);
            O[8] = fmaf(pv, v2.x, O[8]);   O[9] = fmaf(pv, v2.y, O[9]);
            O[10] = fmaf(pv, v2.z, O[10]); O[11] = fmaf(pv, v2.w, O[11]);
            O[12] = fmaf(pv, v3.x, O[12]); O[13] = fmaf(pv, v3.y, O[13]);
            O[14] = fmaf(pv, v3.z, O[14]); O[15] = fmaf(pv, v3.w, O[15]);
        }
    }

    float invl = 1.f / l_r;
    float* op = o + (size_t)(l0 + r) * DM + h * HD + dseg;
    *(float4*)(op) = make_float4(O[0] * invl, O[1] * invl, O[2] * invl, O[3] * invl);
    *(float4*)(op + 4) = make_float4(O[4] * invl, O[5] * invl, O[6] * invl, O[7] * invl);
    *(float4*)(op + 8) = make_float4(O[8] * invl, O[9] * invl, O[10] * invl, O[11] * invl);
    *(float4*)(op + 12) = make_float4(O[12] * invl, O[13] * invl, O[14] * invl, O[15] * invl);
}

// ---------------- conv_out: h[L,DM] (as [DM,L] transposed) -> out[4, L] ----------------
__global__ __launch_bounds__(256) void conv_out_kernel(const float* __restrict__ h,
                                                       const float* __restrict__ w,
                                                       const float* __restrict__ b,
                                                       float* __restrict__ out) {
    int c = blockIdx.x >> 11;
    int l = blockIdx.x & 2047;
    int t = threadIdx.x;
    float acc = 0.f;
    const float* wc = w + c * (DM * 7);
    for (int idx = t; idx < DM * 7; idx += 256) {
        int d = idx / 7;
        int kk = idx - d * 7;
        int tt = l + kk - 6;
        if (tt >= 0) acc = fmaf(h[(size_t)tt * DM + d], wc[idx], acc);
    }
#pragma unroll
    for (int off = 1; off < 64; off <<= 1) acc += __shfl_xor(acc, off, 64);
    __shared__ float red[4];
    if ((t & 63) == 0) red[t >> 6] = acc;
    __syncthreads();
    if (t == 0) out[blockIdx.x] = red[0] + red[1] + red[2] + red[3] + b[c];
}

extern "C" void kernel_launch(void* const* d_in, const int* in_sizes, int n_in,
                              void* d_out, int out_size, void* d_ws, size_t ws_size,
                              hipStream_t stream) {
    const float* x = (const float*)d_in[0];
    const float* conv_in_w = (const float*)d_in[1];
    const float* conv_in_b = (const float*)d_in[2];
    const float* ln1_w = (const float*)d_in[3];
    const float* ln1_b = (const float*)d_in[4];
    const float* wq = (const float*)d_in[5];
    const float* wk = (const float*)d_in[6];
    const float* wv = (const float*)d_in[7];
    const float* wo = (const float*)d_in[8];
    const float* ln2_w = (const float*)d_in[9];
    const float* ln2_b = (const float*)d_in[10];
    const float* w1 = (const float*)d_in[11];
    const float* b1 = (const float*)d_in[12];
    const float* w2 = (const float*)d_in[13];
    const float* b2 = (const float*)d_in[14];
    const float* w3 = (const float*)d_in[15];
    const float* b3 = (const float*)d_in[16];
    const float* conv_out_w = (const float*)d_in[17];
    const float* conv_out_b = (const float*)d_in[18];

    float* ws = (float*)d_ws;
    float* h = ws;                         // 2M floats
    float* hn = ws + 2 * 1024 * 1024;      // 2M
    float* q = ws + 4 * 1024 * 1024;       // 2M
    float* kbuf = ws + 6 * 1024 * 1024;    // 2M
    float* v = ws + 8 * 1024 * 1024;       // 2M
    float* o = ws + 10 * 1024 * 1024;      // 2M
    float* f1 = ws + 12 * 1024 * 1024;     // 8M
    float* f2 = ws + 20 * 1024 * 1024;     // 8M  (total 28M floats = 112 MB)

    conv_in_kernel<<<(L_SEQ * DM) / 256, 256, 0, stream>>>(x, conv_in_w, conv_in_b, h);

    const dim3 g1(DM / 64, L_SEQ / 128);    // N=1024 GEMMs
    const dim3 g2(DFF / 64, L_SEQ / 128);   // N=4096 GEMMs

    for (int layer = 0; layer < 4; ++layer) {
        const float* ln1w = ln1_w + layer * DM;
        const float* ln1b = ln1_b + layer * DM;
        const float* ln2w = ln2_w + layer * DM;
        const float* ln2b = ln2_b + layer * DM;
        const float* wq_l = wq + (size_t)layer * DM * DM;
        const float* wk_l = wk + (size_t)layer * DM * DM;
        const float* wv_l = wv + (size_t)layer * DM * DM;
        const float* wo_l = wo + (size_t)layer * DM * DM;
        const float* w1_l = w1 + (size_t)layer * DFF * DM;
        const float* b1_l = b1 + (size_t)layer * DFF;
        const float* w2_l = w2 + (size_t)layer * DFF * DFF;
        const float* b2_l = b2 + (size_t)layer * DFF;
        const float* w3_l = w3 + (size_t)layer * DM * DFF;
        const float* b3_l = b3 + (size_t)layer * DM;

        rmsnorm_kernel<<<L_SEQ, 256, 0, stream>>>(h, ln1w, ln1b, hn);
        gemm_nt<false, false, false><<<g1, 256, 0, stream>>>(hn, wq_l, nullptr, nullptr, q, L_SEQ, DM, DM);
        gemm_nt<false, false, false><<<g1, 256, 0, stream>>>(hn, wk_l, nullptr, nullptr, kbuf, L_SEQ, DM, DM);
        gemm_nt<false, false, false><<<g1, 256, 0, stream>>>(hn, wv_l, nullptr, nullptr, v, L_SEQ, DM, DM);
        rope_kernel<<<(L_SEQ * NH * 32) / 256, 256, 0, stream>>>(q, kbuf);
        attn_kernel<<<dim3(NH, L_SEQ / 64), 256, 0, stream>>>(q, kbuf, v, o);
        gemm_nt<false, false, true><<<g1, 256, 0, stream>>>(o, wo_l, nullptr, h, h, L_SEQ, DM, DM);
        rmsnorm_kernel<<<L_SEQ, 256, 0, stream>>>(h, ln2w, ln2b, hn);
        gemm_nt<true, true, false><<<g2, 256, 0, stream>>>(hn, w1_l, b1_l, nullptr, f1, L_SEQ, DFF, DM);
        gemm_nt<true, true, false><<<g2, 256, 0, stream>>>(f1, w2_l, b2_l, nullptr, f2, L_SEQ, DFF, DFF);
        gemm_nt<true, false, true><<<g1, 256, 0, stream>>>(f2, w3_l, b3_l, h, h, L_SEQ, DM, DFF);
    }

    conv_out_kernel<<<4 * L_SEQ, 256, 0, stream>>>(h, conv_out_w, conv_out_b, (float*)d_out);
}

// Round 2
// 3022.737 us; speedup vs baseline: 3.1430x; 3.1430x over previous
//
#include <hip/hip_runtime.h>
#include <math.h>

#define L_SEQ 2048
#define DM 1024
#define DFF 4096
#define NH 16
#define HD 64

typedef __bf16 bf16_t;
typedef __bf16 bf16x4 __attribute__((ext_vector_type(4)));
typedef __bf16 bf16x8 __attribute__((ext_vector_type(8)));
typedef float floatx4 __attribute__((ext_vector_type(4)));

__device__ __forceinline__ void gl_lds16(const void* g, void* l) {
    __builtin_amdgcn_global_load_lds((const __attribute__((address_space(1))) void*)g,
                                     (__attribute__((address_space(3))) void*)l, 16, 0, 0);
}

// ---------------- conv_in + relu + transpose: x[4,L] -> h[L, DM] fp32 ----------------
__global__ __launch_bounds__(256) void conv_in_kernel(const float* __restrict__ x,
                                                      const float* __restrict__ w,
                                                      const float* __restrict__ b,
                                                      float* __restrict__ h) {
    int gid = blockIdx.x * 256 + threadIdx.x;
    int d = gid & (DM - 1);
    int l = gid >> 10;
    float acc = b[d];
    const float* wd = w + d * 28;
#pragma unroll
    for (int c = 0; c < 4; ++c) {
#pragma unroll
        for (int k = 0; k < 7; ++k) {
            int t = l + k - 6;
            float xv = (t >= 0) ? x[c * L_SEQ + t] : 0.f;
            acc = fmaf(xv, wd[c * 7 + k], acc);
        }
    }
    h[(size_t)l * DM + d] = fmaxf(acc, 0.f);
}

// ---------------- RMSNorm fp32 in -> bf16 out ----------------
__global__ __launch_bounds__(256) void rmsnorm_kernel(const float* __restrict__ h,
                                                      const float* __restrict__ w,
                                                      const float* __restrict__ b,
                                                      bf16_t* __restrict__ out) {
    int l = blockIdx.x;
    int t = threadIdx.x;
    const float* row = h + (size_t)l * DM;
    float4 xv = *(const float4*)(row + t * 4);
    float ss = xv.x * xv.x + xv.y * xv.y + xv.z * xv.z + xv.w * xv.w;
#pragma unroll
    for (int off = 1; off < 64; off <<= 1) ss += __shfl_xor(ss, off, 64);
    __shared__ float red[4];
    if ((t & 63) == 0) red[t >> 6] = ss;
    __syncthreads();
    float tot = red[0] + red[1] + red[2] + red[3];
    float inv = rsqrtf(tot * (1.f / DM) + 1e-5f);
    float4 wv = *(const float4*)(w + t * 4);
    float4 bv = *(const float4*)(b + t * 4);
    bf16x4 ov;
    ov.x = (bf16_t)fmaf(xv.x * inv, wv.x, bv.x);
    ov.y = (bf16_t)fmaf(xv.y * inv, wv.y, bv.y);
    ov.z = (bf16_t)fmaf(xv.z * inv, wv.z, bv.z);
    ov.w = (bf16_t)fmaf(xv.w * inv, wv.w, bv.w);
    *(bf16x4*)(out + (size_t)l * DM + t * 4) = ov;
}

// ---------------- weight conversion fp32 -> bf16 ----------------
__global__ __launch_bounds__(256) void cvt_bf16(const float* __restrict__ in,
                                                bf16_t* __restrict__ out, int n4) {
    int i = blockIdx.x * 256 + threadIdx.x;
    if (i < n4) {
        float4 v = *(const float4*)(in + (size_t)i * 4);
        bf16x4 o = {(bf16_t)v.x, (bf16_t)v.y, (bf16_t)v.z, (bf16_t)v.w};
        *(bf16x4*)(out + (size_t)i * 4) = o;
    }
}

// wq/wk/wv [4][1024][1024] fp32 -> fused [4][3072][1024] bf16
__global__ __launch_bounds__(256) void cvt_qkvw(const float* __restrict__ wq,
                                                const float* __restrict__ wk,
                                                const float* __restrict__ wv,
                                                bf16_t* __restrict__ out) {
    int i = blockIdx.x * 256 + threadIdx.x;  // < 3145728 float4 groups
    int layer = i / 786432;
    int rem = i - layer * 786432;
    int sel = rem / 262144;
    int idx = rem - sel * 262144;
    const float* src = (sel == 0 ? wq : sel == 1 ? wk : wv) + (size_t)layer * 1048576 + (size_t)idx * 4;
    float4 v = *(const float4*)src;
    bf16x4 o = {(bf16_t)v.x, (bf16_t)v.y, (bf16_t)v.z, (bf16_t)v.w};
    *(bf16x4*)(out + (size_t)i * 4) = o;
}

// ---------------- bf16 MFMA GEMM NT: C[M,N] = A[M,K] * B[N,K]^T (+bias,relu,res) ----------------
// TN=128: 128x128 tile, 4 waves in 2x2, each 4x4 16x16 tiles.
// TN=64:  128x64 tile,  4 waves stacked in m (32 rows each), each 2x4 tiles.
template <int TN, bool BIAS, bool RELU, bool RES, bool OUTBF>
__global__ __launch_bounds__(256) void gemm_bt(const bf16_t* __restrict__ A,
                                               const bf16_t* __restrict__ B,
                                               const float* __restrict__ bias,
                                               const float* __restrict__ res,
                                               void* __restrict__ Cout,
                                               int M, int N, int K) {
    constexpr int WMI = (TN == 128) ? 4 : 2;
    __shared__ alignas(16) bf16_t As[128 * 32];
    __shared__ alignas(16) bf16_t Bs[TN * 32];

    const int t = threadIdx.x;
    const int wave = t >> 6;
    const int lane = t & 63;
    const int quad = lane >> 4;
    const int l16 = lane & 15;
    const int m0 = blockIdx.y * 128;
    const int n0 = blockIdx.x * TN;

    const int wm = (TN == 128) ? (wave & 1) * 64 : wave * 32;
    const int wn = (TN == 128) ? (wave >> 1) * 64 : 0;

    floatx4 acc[WMI][4];
#pragma unroll
    for (int i = 0; i < WMI; ++i)
#pragma unroll
        for (int j = 0; j < 4; ++j) acc[i][j] = (floatx4)0.f;

    const int ldrow = t >> 2;          // 0..63
    const int ldk = (t & 3) * 8;       // k offset in bf16 elems
    const bf16_t* ga = A + (size_t)(m0 + ldrow) * K + ldk;
    const bf16_t* gb = B + (size_t)(n0 + ldrow) * K + ldk;
    char* lA = (char*)As + (size_t)wave * 1024;   // wave-uniform LDS base
    char* lB = (char*)Bs + (size_t)wave * 1024;

    for (int k0 = 0; k0 < K; k0 += 32) {
        gl_lds16(ga, lA);
        gl_lds16(ga + (size_t)64 * K, lA + 4096);
        gl_lds16(gb, lB);
        if (TN == 128) gl_lds16(gb + (size_t)64 * K, lB + 4096);
        ga += 32;
        gb += 32;
        __syncthreads();

        bf16x8 af[WMI], bfr[4];
#pragma unroll
        for (int i = 0; i < WMI; ++i)
            af[i] = *(const bf16x8*)((const char*)As + (size_t)(wm + i * 16 + l16) * 64 + quad * 16);
#pragma unroll
        for (int j = 0; j < 4; ++j)
            bfr[j] = *(const bf16x8*)((const char*)Bs + (size_t)(wn + j * 16 + l16) * 64 + quad * 16);
#pragma unroll
        for (int i = 0; i < WMI; ++i)
#pragma unroll
            for (int j = 0; j < 4; ++j)
                acc[i][j] = __builtin_amdgcn_mfma_f32_16x16x32_bf16(af[i], bfr[j], acc[i][j], 0, 0, 0);
        __syncthreads();
    }

#pragma unroll
    for (int i = 0; i < WMI; ++i) {
        const int m = m0 + wm + i * 16 + quad * 4;
#pragma unroll
        for (int j = 0; j < 4; ++j) {
            const int n = n0 + wn + j * 16 + l16;
            float bv = 0.f;
            if (BIAS) bv = bias[n];
#pragma unroll
            for (int r = 0; r < 4; ++r) {
                float v = acc[i][j][r] + bv;
                if (RELU) v = fmaxf(v, 0.f);
                if (RES) v += res[(size_t)(m + r) * N + n];
                if (OUTBF) ((bf16_t*)Cout)[(size_t)(m + r) * N + n] = (bf16_t)v;
                else ((float*)Cout)[(size_t)(m + r) * N + n] = v;
            }
        }
    }
}

// ---------------- RoPE in-place on fused qkv [L][3072] (q at 0, k at 1024) ----------------
__global__ __launch_bounds__(256) void rope_kernel(float* __restrict__ qkv) {
    int gid = blockIdx.x * 256 + threadIdx.x;  // L*NH*32
    int j = gid & 31;
    int hh = (gid >> 5) & 15;
    int l = gid >> 9;
    float freq = powf(10000.f, -(float)(2 * j) * (1.f / 64.f));
    float ang = (float)l * freq;
    float s = sinf(ang), c = cosf(ang);
    size_t base = (size_t)l * 3072 + hh * HD + j;
    float q1 = qkv[base], q2 = qkv[base + 32];
    qkv[base] = q1 * c - q2 * s;
    qkv[base + 32] = q2 * c + q1 * s;
    size_t kb = base + 1024;
    float k1 = qkv[kb], k2 = qkv[kb + 32];
    qkv[kb] = k1 * c - k2 * s;
    qkv[kb + 32] = k2 * c + k1 * s;
}

// ---------------- Flash-style causal attention fp32, reads fused qkv, writes bf16 o ----------------
__global__ __launch_bounds__(256) void attn_kernel(const float* __restrict__ qkv,
                                                   bf16_t* __restrict__ o) {
    __shared__ float Qs[64][68];
    __shared__ float KP[64][68];
    __shared__ float Vs[64][68];
    const int t = threadIdx.x;
    const int h = blockIdx.x;
    const int qt = blockIdx.y;
    const int l0 = qt * 64;
    const int r = t >> 2;
    const int c4 = t & 3;
    const int dseg = c4 * 16;

#pragma unroll
    for (int i = 0; i < 4; ++i) {
        int f = t + i * 256;
        int row = f >> 4;
        int dd = (f & 15) * 4;
        float4 qv = *(const float4*)(qkv + (size_t)(l0 + row) * 3072 + h * HD + dd);
        qv.x *= 0.125f; qv.y *= 0.125f; qv.z *= 0.125f; qv.w *= 0.125f;
        *(float4*)(&Qs[row][dd]) = qv;
    }

    float m_r = -1e30f, l_r = 0.f;
    float O[16];
#pragma unroll
    for (int i = 0; i < 16; ++i) O[i] = 0.f;

    const int ntiles = qt + 1;
    for (int jt = 0; jt < ntiles; ++jt) {
        const int j0 = jt * 64;
        __syncthreads();
#pragma unroll
        for (int i = 0; i < 4; ++i) {
            int f = t + i * 256;
            int row = f >> 4;
            int dd = (f & 15) * 4;
            float4 kv = *(const float4*)(qkv + (size_t)(j0 + row) * 3072 + 1024 + h * HD + dd);
            KP[dd + 0][row] = kv.x;
            KP[dd + 1][row] = kv.y;
            KP[dd + 2][row] = kv.z;
            KP[dd + 3][row] = kv.w;
            float4 vv = *(const float4*)(qkv + (size_t)(j0 + row) * 3072 + 2048 + h * HD + dd);
            *(float4*)(&Vs[row][dd]) = vv;
        }
        __syncthreads();

        float s[16];
#pragma unroll
        for (int jj = 0; jj < 16; ++jj) s[jj] = 0.f;
#pragma unroll 4
        for (int d = 0; d < 64; ++d) {
            float qv = Qs[r][d];
            float4 k0 = *(const float4*)(&KP[d][dseg]);
            float4 k1 = *(const float4*)(&KP[d][dseg + 4]);
            float4 k2 = *(const float4*)(&KP[d][dseg + 8]);
            float4 k3 = *(const float4*)(&KP[d][dseg + 12]);
            s[0] = fmaf(qv, k0.x, s[0]);   s[1] = fmaf(qv, k0.y, s[1]);
            s[2] = fmaf(qv, k0.z, s[2]);   s[3] = fmaf(qv, k0.w, s[3]);
            s[4] = fmaf(qv, k1.x, s[4]);   s[5] = fmaf(qv, k1.y, s[5]);
            s[6] = fmaf(qv, k1.z, s[6]);   s[7] = fmaf(qv, k1.w, s[7]);
            s[8] = fmaf(qv, k2.x, s[8]);   s[9] = fmaf(qv, k2.y, s[9]);
            s[10] = fmaf(qv, k2.z, s[10]); s[11] = fmaf(qv, k2.w, s[11]);
            s[12] = fmaf(qv, k3.x, s[12]); s[13] = fmaf(qv, k3.y, s[13]);
            s[14] = fmaf(qv, k3.z, s[14]); s[15] = fmaf(qv, k3.w, s[15]);
        }
        if (jt == qt) {
#pragma unroll
            for (int jj = 0; jj < 16; ++jj)
                if (dseg + jj > r) s[jj] = -1e30f;
        }
        float mt = s[0];
#pragma unroll
        for (int jj = 1; jj < 16; ++jj) mt = fmaxf(mt, s[jj]);
        mt = fmaxf(mt, __shfl_xor(mt, 1, 64));
        mt = fmaxf(mt, __shfl_xor(mt, 2, 64));
        float m_new = fmaxf(m_r, mt);
        float alpha = __expf(m_r - m_new);
        float rs = 0.f;
#pragma unroll
        for (int jj = 0; jj < 16; ++jj) {
            float p = __expf(s[jj] - m_new);
            s[jj] = p;
            rs += p;
        }
        rs += __shfl_xor(rs, 1, 64);
        rs += __shfl_xor(rs, 2, 64);
        l_r = l_r * alpha + rs;
        m_r = m_new;
#pragma unroll
        for (int i = 0; i < 16; ++i) O[i] *= alpha;

        __syncthreads();
        *(float4*)(&KP[r][dseg]) = make_float4(s[0], s[1], s[2], s[3]);
        *(float4*)(&KP[r][dseg + 4]) = make_float4(s[4], s[5], s[6], s[7]);
        *(float4*)(&KP[r][dseg + 8]) = make_float4(s[8], s[9], s[10], s[11]);
        *(float4*)(&KP[r][dseg + 12]) = make_float4(s[12], s[13], s[14], s[15]);
        __syncthreads();

#pragma unroll 4
        for (int j = 0; j < 64; ++j) {
            float pv = KP[r][j];
            float4 v0 = *(const float4*)(&Vs[j][dseg]);
            float4 v1 = *(const float4*)(&Vs[j][dseg + 4]);
            float4 v2 = *(const float4*)(&Vs[j][dseg + 8]);
            float4 v3 = *(const float4*)(&Vs[j][dseg + 12]);
            O[0] = fmaf(pv, v0.x, O[0]);   O[1] = fmaf(pv, v0.y, O[1]);
            O[2] = fmaf(pv, v0.z, O[2]);   O[3] = fmaf(pv, v0.w, O[3]);
            O[4] = fmaf(pv, v1.x, O[4]);   O[5] = fmaf(pv, v1.y, O[5]);
            O[6] = fmaf(pv, v1.z, O[6]);   O[7] = fmaf(pv, v1.w, O[7]);
            O[8] = fmaf(pv, v2.x, O[8]);   O[9] = fmaf(pv, v2.y, O[9]);
            O[10] = fmaf(pv, v2.z, O[10]); O[11] = fmaf(pv, v2.w, O[11]);
            O[12] = fmaf(pv, v3.x, O[12]); O[13] = fmaf(pv, v3.y, O[13]);
            O[14] = fmaf(pv, v3.z, O[14]); O[15] = fmaf(pv, v3.w, O[15]);
        }
    }

    float invl = 1.f / l_r;
    bf16_t* op = o + (size_t)(l0 + r) * DM + h * HD + dseg;
    bf16x4 o0 = {(bf16_t)(O[0] * invl), (bf16_t)(O[1] * invl), (bf16_t)(O[2] * invl), (bf16_t)(O[3] * invl)};
    bf16x4 o1 = {(bf16_t)(O[4] * invl), (bf16_t)(O[5] * invl), (bf16_t)(O[6] * invl), (bf16_t)(O[7] * invl)};
    bf16x4 o2 = {(bf16_t)(O[8] * invl), (bf16_t)(O[9] * invl), (bf16_t)(O[10] * invl), (bf16_t)(O[11] * invl)};
    bf16x4 o3 = {(bf16_t)(O[12] * invl), (bf16_t)(O[13] * invl), (bf16_t)(O[14] * invl), (bf16_t)(O[15] * invl)};
    *(bf16x4*)(op) = o0;
    *(bf16x4*)(op + 4) = o1;
    *(bf16x4*)(op + 8) = o2;
    *(bf16x4*)(op + 12) = o3;
}

// ---------------- conv_out: h[L,DM] fp32 -> out[4, L] ----------------
__global__ __launch_bounds__(256) void conv_out_kernel(const float* __restrict__ h,
                                                       const float* __restrict__ w,
                                                       const float* __restrict__ b,
                                                       float* __restrict__ out) {
    int c = blockIdx.x >> 11;
    int l = blockIdx.x & 2047;
    int t = threadIdx.x;
    float acc = 0.f;
    const float* wc = w + c * (DM * 7);
    for (int idx = t; idx < DM * 7; idx += 256) {
        int d = idx / 7;
        int kk = idx - d * 7;
        int tt = l + kk - 6;
        if (tt >= 0) acc = fmaf(h[(size_t)tt * DM + d], wc[idx], acc);
    }
#pragma unroll
    for (int off = 1; off < 64; off <<= 1) acc += __shfl_xor(acc, off, 64);
    __shared__ float red[4];
    if ((t & 63) == 0) red[t >> 6] = acc;
    __syncthreads();
    if (t == 0) out[blockIdx.x] = red[0] + red[1] + red[2] + red[3] + b[c];
}

extern "C" void kernel_launch(void* const* d_in, const int* in_sizes, int n_in,
                              void* d_out, int out_size, void* d_ws, size_t ws_size,
                              hipStream_t stream) {
    const float* x = (const float*)d_in[0];
    const float* conv_in_w = (const float*)d_in[1];
    const float* conv_in_b = (const float*)d_in[2];
    const float* ln1_w = (const float*)d_in[3];
    const float* ln1_b = (const float*)d_in[4];
    const float* wq = (const float*)d_in[5];
    const float* wk = (const float*)d_in[6];
    const float* wv = (const float*)d_in[7];
    const float* wo = (const float*)d_in[8];
    const float* ln2_w = (const float*)d_in[9];
    const float* ln2_b = (const float*)d_in[10];
    const float* w1 = (const float*)d_in[11];
    const float* b1 = (const float*)d_in[12];
    const float* w2 = (const float*)d_in[13];
    const float* b2 = (const float*)d_in[14];
    const float* w3 = (const float*)d_in[15];
    const float* b3 = (const float*)d_in[16];
    const float* conv_out_w = (const float*)d_in[17];
    const float* conv_out_b = (const float*)d_in[18];

    char* W = (char*)d_ws;
    float* h = (float*)(W);                                  // 8 MB  [2048,1024] fp32
    float* qkv = (float*)(W + (8ull << 20));                 // 24 MB [2048,3072] fp32
    bf16_t* hn = (bf16_t*)(W + (32ull << 20));               // 4 MB  [2048,1024] bf16
    bf16_t* ob = (bf16_t*)(W + (36ull << 20));               // 4 MB  [2048,1024] bf16
    bf16_t* f1 = (bf16_t*)(W + (40ull << 20));               // 16 MB [2048,4096] bf16
    bf16_t* f2 = (bf16_t*)(W + (56ull << 20));               // 16 MB [2048,4096] bf16
    bf16_t* qkvw = (bf16_t*)(W + (72ull << 20));             // 24 MB [4][3072,1024] bf16
    bf16_t* wob = (bf16_t*)(W + (96ull << 20));              // 8 MB
    bf16_t* w1b = (bf16_t*)(W + (104ull << 20));             // 32 MB
    bf16_t* w2b = (bf16_t*)(W + (136ull << 20));             // 128 MB
    bf16_t* w3b = (bf16_t*)(W + (264ull << 20));             // 32 MB (end: 296 MB)

    // weight conversions (each replay; ~672 MB traffic)
    cvt_qkvw<<<12288, 256, 0, stream>>>(wq, wk, wv, qkvw);
    cvt_bf16<<<4096, 256, 0, stream>>>(wo, wob, 1048576);
    cvt_bf16<<<16384, 256, 0, stream>>>(w1, w1b, 4194304);
    cvt_bf16<<<65536, 256, 0, stream>>>(w2, w2b, 16777216);
    cvt_bf16<<<16384, 256, 0, stream>>>(w3, w3b, 4194304);

    conv_in_kernel<<<(L_SEQ * DM) / 256, 256, 0, stream>>>(x, conv_in_w, conv_in_b, h);

    for (int layer = 0; layer < 4; ++layer) {
        const float* ln1w = ln1_w + layer * DM;
        const float* ln1b = ln1_b + layer * DM;
        const float* ln2w = ln2_w + layer * DM;
        const float* ln2b = ln2_b + layer * DM;
        const bf16_t* qkvw_l = qkvw + (size_t)layer * 3072 * 1024;
        const bf16_t* wob_l = wob + (size_t)layer * DM * DM;
        const bf16_t* w1b_l = w1b + (size_t)layer * DFF * DM;
        const bf16_t* w2b_l = w2b + (size_t)layer * DFF * DFF;
        const bf16_t* w3b_l = w3b + (size_t)layer * DM * DFF;
        const float* b1_l = b1 + (size_t)layer * DFF;
        const float* b2_l = b2 + (size_t)layer * DFF;
        const float* b3_l = b3 + (size_t)layer * DM;

        rmsnorm_kernel<<<L_SEQ, 256, 0, stream>>>(h, ln1w, ln1b, hn);
        gemm_bt<128, false, false, false, false><<<dim3(3072 / 128, L_SEQ / 128), 256, 0, stream>>>(
            hn, qkvw_l, nullptr, nullptr, qkv, L_SEQ, 3072, 1024);
        rope_kernel<<<(L_SEQ * NH * 32) / 256, 256, 0, stream>>>(qkv);
        attn_kernel<<<dim3(NH, L_SEQ / 64), 256, 0, stream>>>(qkv, ob);
        gemm_bt<64, false, false, true, false><<<dim3(DM / 64, L_SEQ / 128), 256, 0, stream>>>(
            ob, wob_l, nullptr, h, h, L_SEQ, DM, DM);
        rmsnorm_kernel<<<L_SEQ, 256, 0, stream>>>(h, ln2w, ln2b, hn);
        gemm_bt<128, true, true, false, true><<<dim3(DFF / 128, L_SEQ / 128), 256, 0, stream>>>(
            hn, w1b_l, b1_l, nullptr, f1, L_SEQ, DFF, 1024);
        gemm_bt<128, true, true, false, true><<<dim3(DFF / 128, L_SEQ / 128), 256, 0, stream>>>(
            f1, w2b_l, b2_l, nullptr, f2, L_SEQ, DFF, DFF);
        gemm_bt<64, true, false, true, false><<<dim3(DM / 64, L_SEQ / 128), 256, 0, stream>>>(
            f2, w3b_l, b3_l, h, h, L_SEQ, DM, DFF);
    }

    conv_out_kernel<<<4 * L_SEQ, 256, 0, stream>>>(h, conv_out_w, conv_out_b, (float*)d_out);
}

// Round 3
// 2195.458 us; speedup vs baseline: 4.3274x; 1.3768x over previous
//
#include <hip/hip_runtime.h>
#include <math.h>

#define L_SEQ 2048
#define DM 1024
#define DFF 4096
#define NH 16
#define HD 64

typedef __bf16 bf16_t;
typedef __bf16 bf16x4 __attribute__((ext_vector_type(4)));
typedef __bf16 bf16x8 __attribute__((ext_vector_type(8)));
typedef float floatx4 __attribute__((ext_vector_type(4)));

__device__ __forceinline__ void gl_lds16(const void* g, void* l) {
    __builtin_amdgcn_global_load_lds((const __attribute__((address_space(1))) void*)g,
                                     (__attribute__((address_space(3))) void*)l, 16, 0, 0);
}

// ---------------- conv_in + relu + transpose: x[4,L] -> h[L, DM] fp32 ----------------
__global__ __launch_bounds__(256) void conv_in_kernel(const float* __restrict__ x,
                                                      const float* __restrict__ w,
                                                      const float* __restrict__ b,
                                                      float* __restrict__ h) {
    int gid = blockIdx.x * 256 + threadIdx.x;
    int d = gid & (DM - 1);
    int l = gid >> 10;
    float acc = b[d];
    const float* wd = w + d * 28;
#pragma unroll
    for (int c = 0; c < 4; ++c) {
#pragma unroll
        for (int k = 0; k < 7; ++k) {
            int t = l + k - 6;
            float xv = (t >= 0) ? x[c * L_SEQ + t] : 0.f;
            acc = fmaf(xv, wd[c * 7 + k], acc);
        }
    }
    h[(size_t)l * DM + d] = fmaxf(acc, 0.f);
}

// ---------------- RMSNorm fp32 in -> bf16 out ----------------
__global__ __launch_bounds__(256) void rmsnorm_kernel(const float* __restrict__ h,
                                                      const float* __restrict__ w,
                                                      const float* __restrict__ b,
                                                      bf16_t* __restrict__ out) {
    int l = blockIdx.x;
    int t = threadIdx.x;
    const float* row = h + (size_t)l * DM;
    float4 xv = *(const float4*)(row + t * 4);
    float ss = xv.x * xv.x + xv.y * xv.y + xv.z * xv.z + xv.w * xv.w;
#pragma unroll
    for (int off = 1; off < 64; off <<= 1) ss += __shfl_xor(ss, off, 64);
    __shared__ float red[4];
    if ((t & 63) == 0) red[t >> 6] = ss;
    __syncthreads();
    float tot = red[0] + red[1] + red[2] + red[3];
    float inv = rsqrtf(tot * (1.f / DM) + 1e-5f);
    float4 wv = *(const float4*)(w + t * 4);
    float4 bv = *(const float4*)(b + t * 4);
    bf16x4 ov;
    ov.x = (bf16_t)fmaf(xv.x * inv, wv.x, bv.x);
    ov.y = (bf16_t)fmaf(xv.y * inv, wv.y, bv.y);
    ov.z = (bf16_t)fmaf(xv.z * inv, wv.z, bv.z);
    ov.w = (bf16_t)fmaf(xv.w * inv, wv.w, bv.w);
    *(bf16x4*)(out + (size_t)l * DM + t * 4) = ov;
}

// ---------------- weight conversion fp32 -> bf16 ----------------
__global__ __launch_bounds__(256) void cvt_bf16(const float* __restrict__ in,
                                                bf16_t* __restrict__ out, int n4) {
    int i = blockIdx.x * 256 + threadIdx.x;
    if (i < n4) {
        float4 v = *(const float4*)(in + (size_t)i * 4);
        bf16x4 o = {(bf16_t)v.x, (bf16_t)v.y, (bf16_t)v.z, (bf16_t)v.w};
        *(bf16x4*)(out + (size_t)i * 4) = o;
    }
}

// wq/wk/wv [4][1024][1024] fp32 -> fused [4][3072][1024] bf16
__global__ __launch_bounds__(256) void cvt_qkvw(const float* __restrict__ wq,
                                                const float* __restrict__ wk,
                                                const float* __restrict__ wv,
                                                bf16_t* __restrict__ out) {
    int i = blockIdx.x * 256 + threadIdx.x;
    int layer = i / 786432;
    int rem = i - layer * 786432;
    int sel = rem / 262144;
    int idx = rem - sel * 262144;
    const float* src = (sel == 0 ? wq : sel == 1 ? wk : wv) + (size_t)layer * 1048576 + (size_t)idx * 4;
    float4 v = *(const float4*)src;
    bf16x4 o = {(bf16_t)v.x, (bf16_t)v.y, (bf16_t)v.z, (bf16_t)v.w};
    *(bf16x4*)(out + (size_t)i * 4) = o;
}

// ---------------- bf16 MFMA GEMM NT ----------------
template <int TN, bool BIAS, bool RELU, bool RES, bool OUTBF>
__global__ __launch_bounds__(256) void gemm_bt(const bf16_t* __restrict__ A,
                                               const bf16_t* __restrict__ B,
                                               const float* __restrict__ bias,
                                               const float* __restrict__ res,
                                               void* __restrict__ Cout,
                                               int M, int N, int K) {
    constexpr int WMI = (TN == 128) ? 4 : 2;
    __shared__ alignas(16) bf16_t As[128 * 32];
    __shared__ alignas(16) bf16_t Bs[TN * 32];

    const int t = threadIdx.x;
    const int wave = t >> 6;
    const int lane = t & 63;
    const int quad = lane >> 4;
    const int l16 = lane & 15;
    const int m0 = blockIdx.y * 128;
    const int n0 = blockIdx.x * TN;

    const int wm = (TN == 128) ? (wave & 1) * 64 : wave * 32;
    const int wn = (TN == 128) ? (wave >> 1) * 64 : 0;

    floatx4 acc[WMI][4];
#pragma unroll
    for (int i = 0; i < WMI; ++i)
#pragma unroll
        for (int j = 0; j < 4; ++j) acc[i][j] = (floatx4)0.f;

    const int ldrow = t >> 2;
    const int ldk = (t & 3) * 8;
    const bf16_t* ga = A + (size_t)(m0 + ldrow) * K + ldk;
    const bf16_t* gb = B + (size_t)(n0 + ldrow) * K + ldk;
    char* lA = (char*)As + (size_t)wave * 1024;
    char* lB = (char*)Bs + (size_t)wave * 1024;

    for (int k0 = 0; k0 < K; k0 += 32) {
        gl_lds16(ga, lA);
        gl_lds16(ga + (size_t)64 * K, lA + 4096);
        gl_lds16(gb, lB);
        if (TN == 128) gl_lds16(gb + (size_t)64 * K, lB + 4096);
        ga += 32;
        gb += 32;
        __syncthreads();

        bf16x8 af[WMI], bfr[4];
#pragma unroll
        for (int i = 0; i < WMI; ++i)
            af[i] = *(const bf16x8*)((const char*)As + (size_t)(wm + i * 16 + l16) * 64 + quad * 16);
#pragma unroll
        for (int j = 0; j < 4; ++j)
            bfr[j] = *(const bf16x8*)((const char*)Bs + (size_t)(wn + j * 16 + l16) * 64 + quad * 16);
#pragma unroll
        for (int i = 0; i < WMI; ++i)
#pragma unroll
            for (int j = 0; j < 4; ++j)
                acc[i][j] = __builtin_amdgcn_mfma_f32_16x16x32_bf16(af[i], bfr[j], acc[i][j], 0, 0, 0);
        __syncthreads();
    }

#pragma unroll
    for (int i = 0; i < WMI; ++i) {
        const int m = m0 + wm + i * 16 + quad * 4;
#pragma unroll
        for (int j = 0; j < 4; ++j) {
            const int n = n0 + wn + j * 16 + l16;
            float bv = 0.f;
            if (BIAS) bv = bias[n];
#pragma unroll
            for (int r = 0; r < 4; ++r) {
                float v = acc[i][j][r] + bv;
                if (RELU) v = fmaxf(v, 0.f);
                if (RES) v += res[(size_t)(m + r) * N + n];
                if (OUTBF) ((bf16_t*)Cout)[(size_t)(m + r) * N + n] = (bf16_t)v;
                else ((float*)Cout)[(size_t)(m + r) * N + n] = v;
            }
        }
    }
}

// ---------------- RoPE in-place on fused bf16 qkv [L][3072] ----------------
__global__ __launch_bounds__(256) void rope_kernel(bf16_t* __restrict__ qkv) {
    int gid = blockIdx.x * 256 + threadIdx.x;  // L*NH*32
    int j = gid & 31;
    int hh = (gid >> 5) & 15;
    int l = gid >> 9;
    float freq = powf(10000.f, -(float)(2 * j) * (1.f / 64.f));
    float ang = (float)l * freq;
    float s = sinf(ang), c = cosf(ang);
    size_t base = (size_t)l * 3072 + hh * HD + j;
    float q1 = (float)qkv[base], q2 = (float)qkv[base + 32];
    qkv[base] = (bf16_t)(q1 * c - q2 * s);
    qkv[base + 32] = (bf16_t)(q2 * c + q1 * s);
    size_t kb = base + 1024;
    float k1 = (float)qkv[kb], k2 = (float)qkv[kb + 32];
    qkv[kb] = (bf16_t)(k1 * c - k2 * s);
    qkv[kb + 32] = (bf16_t)(k2 * c + k1 * s);
}

// ---------------- V transpose: qkvb v-part [token][h*64+d] -> vt[h][d][token] ----------------
__global__ __launch_bounds__(256) void v_transpose(const bf16_t* __restrict__ qkvb,
                                                   bf16_t* __restrict__ vt) {
    __shared__ bf16_t Ts[64 * 72];
    const int h = blockIdx.x;
    const int tt = blockIdx.y;
    const int t = threadIdx.x;
#pragma unroll
    for (int i = 0; i < 2; ++i) {
        int idx = t + i * 256;
        int row = idx >> 3, dg = idx & 7;
        *(bf16x8*)(Ts + row * 72 + dg * 8) =
            *(const bf16x8*)(qkvb + (size_t)(tt * 64 + row) * 3072 + 2048 + h * 64 + dg * 8);
    }
    __syncthreads();
#pragma unroll
    for (int i = 0; i < 2; ++i) {
        int idx = t + i * 256;
        int d = idx >> 3, tg = idx & 7;
        bf16x8 v;
#pragma unroll
        for (int s = 0; s < 8; ++s) v[s] = Ts[(tg * 8 + s) * 72 + d];
        *(bf16x8*)(vt + ((size_t)h * 64 + d) * 2048 + tt * 64 + tg * 8) = v;
    }
}

// ---------------- MFMA flash attention (bf16 in/out, fp32 softmax) ----------------
// grid (NH, 32). Block: head h, 64-row q-tile. 4 waves x 16 q-rows each.
__global__ __launch_bounds__(256) void attn_mfma(const bf16_t* __restrict__ qkvb,
                                                 const bf16_t* __restrict__ vt,
                                                 bf16_t* __restrict__ o) {
    __shared__ alignas(16) bf16_t Qs[64 * 72];
    __shared__ alignas(16) bf16_t Ks[64 * 72];
    __shared__ alignas(16) bf16_t Vs[64 * 72];   // [dim][key]
    __shared__ alignas(16) bf16_t Ps[4][16 * 72];
    const int t = threadIdx.x;
    const int wave = t >> 6;
    const int lane = t & 63;
    const int quad = lane >> 4;
    const int l16 = lane & 15;
    const int h = blockIdx.x;
    const int y = blockIdx.y;
    const int qt = (y < 16) ? (31 - y) : (y - 16);   // heavy/light pairing per CU
    const int l0 = qt * 64;

#pragma unroll
    for (int i = 0; i < 2; ++i) {
        int idx = t + i * 256;
        int row = idx >> 3, dg = idx & 7;
        *(bf16x8*)(Qs + row * 72 + dg * 8) =
            *(const bf16x8*)(qkvb + (size_t)(l0 + row) * 3072 + h * HD + dg * 8);
    }

    float m_r[4], l_r[4];
    floatx4 acc_o[4];
#pragma unroll
    for (int r = 0; r < 4; ++r) { m_r[r] = -1e30f; l_r[r] = 0.f; }
#pragma unroll
    for (int n = 0; n < 4; ++n) acc_o[n] = (floatx4)0.f;

    for (int jt = 0; jt <= qt; ++jt) {
        const int j0 = jt * 64;
        __syncthreads();
#pragma unroll
        for (int i = 0; i < 2; ++i) {
            int idx = t + i * 256;
            int row = idx >> 3, dg = idx & 7;
            *(bf16x8*)(Ks + row * 72 + dg * 8) =
                *(const bf16x8*)(qkvb + (size_t)(j0 + row) * 3072 + 1024 + h * HD + dg * 8);
            *(bf16x8*)(Vs + row * 72 + dg * 8) =
                *(const bf16x8*)(vt + ((size_t)h * HD + row) * 2048 + j0 + dg * 8);
        }
        __syncthreads();

        // S = Q K^T : wave's 16 q-rows x 64 keys
        bf16x8 aq0 = *(const bf16x8*)(Qs + (wave * 16 + l16) * 72 + quad * 8);
        bf16x8 aq1 = *(const bf16x8*)(Qs + (wave * 16 + l16) * 72 + 32 + quad * 8);
        floatx4 sacc[4];
#pragma unroll
        for (int j = 0; j < 4; ++j) {
            bf16x8 bk0 = *(const bf16x8*)(Ks + (j * 16 + l16) * 72 + quad * 8);
            bf16x8 bk1 = *(const bf16x8*)(Ks + (j * 16 + l16) * 72 + 32 + quad * 8);
            floatx4 s = (floatx4)0.f;
            s = __builtin_amdgcn_mfma_f32_16x16x32_bf16(aq0, bk0, s, 0, 0, 0);
            s = __builtin_amdgcn_mfma_f32_16x16x32_bf16(aq1, bk1, s, 0, 0, 0);
            sacc[j] = s;
        }

        // online softmax in fp32 on C-layout (row=quad*4+r, col=j*16+l16)
        const bool diag = (jt == qt);
        float mt[4];
#pragma unroll
        for (int r = 0; r < 4; ++r) mt[r] = -1e30f;
#pragma unroll
        for (int j = 0; j < 4; ++j)
#pragma unroll
            for (int r = 0; r < 4; ++r) {
                float sv = sacc[j][r] * 0.125f;
                if (diag && (j * 16 + l16) > (wave * 16 + quad * 4 + r)) sv = -1e30f;
                sacc[j][r] = sv;
                mt[r] = fmaxf(mt[r], sv);
            }
#pragma unroll
        for (int r = 0; r < 4; ++r) {
            mt[r] = fmaxf(mt[r], __shfl_xor(mt[r], 1, 64));
            mt[r] = fmaxf(mt[r], __shfl_xor(mt[r], 2, 64));
            mt[r] = fmaxf(mt[r], __shfl_xor(mt[r], 4, 64));
            mt[r] = fmaxf(mt[r], __shfl_xor(mt[r], 8, 64));
        }
        float alpha[4], rs[4];
#pragma unroll
        for (int r = 0; r < 4; ++r) {
            float mn = fmaxf(m_r[r], mt[r]);
            alpha[r] = __expf(m_r[r] - mn);
            m_r[r] = mn;
            rs[r] = 0.f;
        }
#pragma unroll
        for (int j = 0; j < 4; ++j)
#pragma unroll
            for (int r = 0; r < 4; ++r) {
                float p = __expf(sacc[j][r] - m_r[r]);
                sacc[j][r] = p;
                rs[r] += p;
            }
#pragma unroll
        for (int r = 0; r < 4; ++r) {
            rs[r] += __shfl_xor(rs[r], 1, 64);
            rs[r] += __shfl_xor(rs[r], 2, 64);
            rs[r] += __shfl_xor(rs[r], 4, 64);
            rs[r] += __shfl_xor(rs[r], 8, 64);
            l_r[r] = l_r[r] * alpha[r] + rs[r];
        }
#pragma unroll
        for (int n = 0; n < 4; ++n)
#pragma unroll
            for (int r = 0; r < 4; ++r) acc_o[n][r] *= alpha[r];

        // P (bf16) -> per-wave LDS (C-layout -> A-layout transform)
        bf16_t* pw = Ps[wave];
#pragma unroll
        for (int j = 0; j < 4; ++j)
#pragma unroll
            for (int r = 0; r < 4; ++r)
                pw[(quad * 4 + r) * 72 + j * 16 + l16] = (bf16_t)sacc[j][r];

        // O += P V  (B' = V[key][dim] via Vs[dim][key])
        bf16x8 ap0 = *(const bf16x8*)(pw + l16 * 72 + quad * 8);
        bf16x8 ap1 = *(const bf16x8*)(pw + l16 * 72 + 32 + quad * 8);
#pragma unroll
        for (int n = 0; n < 4; ++n) {
            bf16x8 bv0 = *(const bf16x8*)(Vs + (n * 16 + l16) * 72 + quad * 8);
            bf16x8 bv1 = *(const bf16x8*)(Vs + (n * 16 + l16) * 72 + 32 + quad * 8);
            acc_o[n] = __builtin_amdgcn_mfma_f32_16x16x32_bf16(ap0, bv0, acc_o[n], 0, 0, 0);
            acc_o[n] = __builtin_amdgcn_mfma_f32_16x16x32_bf16(ap1, bv1, acc_o[n], 0, 0, 0);
        }
    }

#pragma unroll
    for (int r = 0; r < 4; ++r) {
        float inv = 1.f / l_r[r];
        int row = l0 + wave * 16 + quad * 4 + r;
#pragma unroll
        for (int n = 0; n < 4; ++n)
            o[(size_t)row * DM + h * HD + n * 16 + l16] = (bf16_t)(acc_o[n][r] * inv);
    }
}

// ---------------- conv_out: h[L,DM] fp32 -> out[4, L] ----------------
__global__ __launch_bounds__(256) void conv_out_kernel(const float* __restrict__ h,
                                                       const float* __restrict__ w,
                                                       const float* __restrict__ b,
                                                       float* __restrict__ out) {
    int c = blockIdx.x >> 11;
    int l = blockIdx.x & 2047;
    int t = threadIdx.x;
    float acc = 0.f;
    const float* wc = w + c * (DM * 7);
    for (int idx = t; idx < DM * 7; idx += 256) {
        int d = idx / 7;
        int kk = idx - d * 7;
        int tt = l + kk - 6;
        if (tt >= 0) acc = fmaf(h[(size_t)tt * DM + d], wc[idx], acc);
    }
#pragma unroll
    for (int off = 1; off < 64; off <<= 1) acc += __shfl_xor(acc, off, 64);
    __shared__ float red[4];
    if ((t & 63) == 0) red[t >> 6] = acc;
    __syncthreads();
    if (t == 0) out[blockIdx.x] = red[0] + red[1] + red[2] + red[3] + b[c];
}

extern "C" void kernel_launch(void* const* d_in, const int* in_sizes, int n_in,
                              void* d_out, int out_size, void* d_ws, size_t ws_size,
                              hipStream_t stream) {
    const float* x = (const float*)d_in[0];
    const float* conv_in_w = (const float*)d_in[1];
    const float* conv_in_b = (const float*)d_in[2];
    const float* ln1_w = (const float*)d_in[3];
    const float* ln1_b = (const float*)d_in[4];
    const float* wq = (const float*)d_in[5];
    const float* wk = (const float*)d_in[6];
    const float* wv = (const float*)d_in[7];
    const float* wo = (const float*)d_in[8];
    const float* ln2_w = (const float*)d_in[9];
    const float* ln2_b = (const float*)d_in[10];
    const float* w1 = (const float*)d_in[11];
    const float* b1 = (const float*)d_in[12];
    const float* w2 = (const float*)d_in[13];
    const float* b2 = (const float*)d_in[14];
    const float* w3 = (const float*)d_in[15];
    const float* b3 = (const float*)d_in[16];
    const float* conv_out_w = (const float*)d_in[17];
    const float* conv_out_b = (const float*)d_in[18];

    char* W = (char*)d_ws;
    float* h = (float*)(W);                                  // 8 MB
    bf16_t* qkvb = (bf16_t*)(W + (8ull << 20));              // 12 MB [2048][3072] bf16
    bf16_t* hn = (bf16_t*)(W + (20ull << 20));               // 4 MB
    bf16_t* ob = (bf16_t*)(W + (24ull << 20));               // 4 MB
    bf16_t* f1 = (bf16_t*)(W + (28ull << 20));               // 16 MB
    bf16_t* f2 = (bf16_t*)(W + (44ull << 20));               // 16 MB
    bf16_t* vtb = (bf16_t*)(W + (60ull << 20));              // 4 MB [16][64][2048] bf16
    bf16_t* qkvw = (bf16_t*)(W + (64ull << 20));             // 24 MB
    bf16_t* wob = (bf16_t*)(W + (88ull << 20));              // 8 MB
    bf16_t* w1b = (bf16_t*)(W + (96ull << 20));              // 32 MB
    bf16_t* w2b = (bf16_t*)(W + (128ull << 20));             // 128 MB
    bf16_t* w3b = (bf16_t*)(W + (256ull << 20));             // 32 MB (end 288 MB)

    cvt_qkvw<<<12288, 256, 0, stream>>>(wq, wk, wv, qkvw);
    cvt_bf16<<<4096, 256, 0, stream>>>(wo, wob, 1048576);
    cvt_bf16<<<16384, 256, 0, stream>>>(w1, w1b, 4194304);
    cvt_bf16<<<65536, 256, 0, stream>>>(w2, w2b, 16777216);
    cvt_bf16<<<16384, 256, 0, stream>>>(w3, w3b, 4194304);

    conv_in_kernel<<<(L_SEQ * DM) / 256, 256, 0, stream>>>(x, conv_in_w, conv_in_b, h);

    for (int layer = 0; layer < 4; ++layer) {
        const float* ln1w = ln1_w + layer * DM;
        const float* ln1b = ln1_b + layer * DM;
        const float* ln2w = ln2_w + layer * DM;
        const float* ln2b = ln2_b + layer * DM;
        const bf16_t* qkvw_l = qkvw + (size_t)layer * 3072 * 1024;
        const bf16_t* wob_l = wob + (size_t)layer * DM * DM;
        const bf16_t* w1b_l = w1b + (size_t)layer * DFF * DM;
        const bf16_t* w2b_l = w2b + (size_t)layer * DFF * DFF;
        const bf16_t* w3b_l = w3b + (size_t)layer * DM * DFF;
        const float* b1_l = b1 + (size_t)layer * DFF;
        const float* b2_l = b2 + (size_t)layer * DFF;
        const float* b3_l = b3 + (size_t)layer * DM;

        rmsnorm_kernel<<<L_SEQ, 256, 0, stream>>>(h, ln1w, ln1b, hn);
        gemm_bt<128, false, false, false, true><<<dim3(3072 / 128, L_SEQ / 128), 256, 0, stream>>>(
            hn, qkvw_l, nullptr, nullptr, qkvb, L_SEQ, 3072, 1024);
        rope_kernel<<<(L_SEQ * NH * 32) / 256, 256, 0, stream>>>(qkvb);
        v_transpose<<<dim3(NH, L_SEQ / 64), 256, 0, stream>>>(qkvb, vtb);
        attn_mfma<<<dim3(NH, L_SEQ / 64), 256, 0, stream>>>(qkvb, vtb, ob);
        gemm_bt<64, false, false, true, false><<<dim3(DM / 64, L_SEQ / 128), 256, 0, stream>>>(
            ob, wob_l, nullptr, h, h, L_SEQ, DM, DM);
        rmsnorm_kernel<<<L_SEQ, 256, 0, stream>>>(h, ln2w, ln2b, hn);
        gemm_bt<128, true, true, false, true><<<dim3(DFF / 128, L_SEQ / 128), 256, 0, stream>>>(
            hn, w1b_l, b1_l, nullptr, f1, L_SEQ, DFF, 1024);
        gemm_bt<128, true, true, false, true><<<dim3(DFF / 128, L_SEQ / 128), 256, 0, stream>>>(
            f1, w2b_l, b2_l, nullptr, f2, L_SEQ, DFF, DFF);
        gemm_bt<64, true, false, true, false><<<dim3(DM / 64, L_SEQ / 128), 256, 0, stream>>>(
            f2, w3b_l, b3_l, h, h, L_SEQ, DM, DFF);
    }

    conv_out_kernel<<<4 * L_SEQ, 256, 0, stream>>>(h, conv_out_w, conv_out_b, (float*)d_out);
}